// Round 11
// baseline (334.495 us; speedup 1.0000x reference)
//
#include <hip/hip_runtime.h>
#include <stdint.h>
#include <math.h>

// Problem constants
#define NPTS 32768
#define PP   5
#define MM   1024
#define JJ   24
#define HH   256

// out (f32 element offsets), total 2,293,760 floats
#define O0 0                // tpose        [1,N,P,3]
#define O1 491520           // tpose_dirs   [1,N,P,3]
#define O2 983040           // resd         [1,N,P,3]
#define O3 1474560          // pflag        [1,N,P]
#define O4 1638400          // init_bigpose [1,N*P,3]
#define O5 2129920          // pnorm        [1,N*P]

typedef unsigned short ushort_t;
typedef unsigned int   uint_t;
typedef __attribute__((ext_vector_type(8))) short bf16x8;
typedef __attribute__((ext_vector_type(4))) float f32x4;

__device__ __forceinline__ ushort_t f2bf(float f) {
  union { uint_t i; float f; } v; v.f = f;
  uint_t i = v.i;
  return (ushort_t)((i + 0x7FFFu + ((i >> 16) & 1u)) >> 16);  // RNE
}
__device__ __forceinline__ float tanh_fast(float v) {
  v = fminf(fmaxf(v, -15.f), 15.f);
  float e = __expf(2.f*v);
  return __fdividef(e - 1.f, e + 1.f);   // abs err < 1e-6
}

// ---------------- prep: W2 f32 -> bf16 in MFMA B-fragment order ----------------
// idx = kc*8192 + tile*512 + lane*8 + j  (lane=quad*16+(n&15), quad=(k&31)>>3, j=k&7)
__global__ __launch_bounds__(256) void prep_w2(const float* __restrict__ W2g,
                                               ushort_t* __restrict__ W2bf)
{
  int k = blockIdx.x;
  int n = threadIdx.x;
  float v = W2g[k*256 + n];
  int kc = k >> 5, quad = (k & 31) >> 3, j = k & 7;
  int tile = n >> 4, lane = quad*16 + (n & 15);
  W2bf[kc*8192 + tile*512 + lane*8 + j] = f2bf(v);
}

// ---------------- LBS transform for one (n,p) row ----------------
__device__ __forceinline__ void transform_one(
    int n, int p, int nn, float pn, float fl,
    float px, float py, float pz, float dx, float dy, float dz,
    const float* __restrict__ pbw,
    const float4* __restrict__ sA4, const float4* __restrict__ sB4,
    float* __restrict__ out)
{
  const float4* bwr = (const float4*)(pbw + ((size_t)p * MM + nn) * JJ);
  float bw[24];
  #pragma unroll
  for (int q = 0; q < 6; ++q) {
    float4 u = bwr[q];
    bw[q*4+0] = u.x; bw[q*4+1] = u.y; bw[q*4+2] = u.z; bw[q*4+3] = u.w;
  }

  float M1[12], M2[12];
  #pragma unroll
  for (int q = 0; q < 12; ++q) { M1[q] = 0.f; M2[q] = 0.f; }
  #pragma unroll
  for (int j = 0; j < 24; ++j) {
    float w = bw[j];
    float4 a0 = sA4[j*3+0], a1 = sA4[j*3+1], a2 = sA4[j*3+2];
    M1[0]=fmaf(w,a0.x,M1[0]); M1[1]=fmaf(w,a0.y,M1[1]); M1[2]=fmaf(w,a0.z,M1[2]); M1[3]=fmaf(w,a0.w,M1[3]);
    M1[4]=fmaf(w,a1.x,M1[4]); M1[5]=fmaf(w,a1.y,M1[5]); M1[6]=fmaf(w,a1.z,M1[6]); M1[7]=fmaf(w,a1.w,M1[7]);
    M1[8]=fmaf(w,a2.x,M1[8]); M1[9]=fmaf(w,a2.y,M1[9]); M1[10]=fmaf(w,a2.z,M1[10]); M1[11]=fmaf(w,a2.w,M1[11]);
    float4 c0 = sB4[j*3+0], c1 = sB4[j*3+1], c2 = sB4[j*3+2];
    M2[0]=fmaf(w,c0.x,M2[0]); M2[1]=fmaf(w,c0.y,M2[1]); M2[2]=fmaf(w,c0.z,M2[2]); M2[3]=fmaf(w,c0.w,M2[3]);
    M2[4]=fmaf(w,c1.x,M2[4]); M2[5]=fmaf(w,c1.y,M2[5]); M2[6]=fmaf(w,c1.z,M2[6]); M2[7]=fmaf(w,c1.w,M2[7]);
    M2[8]=fmaf(w,c2.x,M2[8]); M2[9]=fmaf(w,c2.y,M2[9]); M2[10]=fmaf(w,c2.z,M2[10]); M2[11]=fmaf(w,c2.w,M2[11]);
  }
  float a=M1[0], b=M1[1], c=M1[2];
  float d=M1[4], e=M1[5], f=M1[6];
  float g=M1[8], h=M1[9], i=M1[10];
  float C00 = e*i - f*h, C01 = c*h - b*i, C02 = b*f - c*e;
  float C10 = f*g - d*i, C11 = a*i - c*g, C12 = c*d - a*f;
  float C20 = d*h - e*g, C21 = b*g - a*h, C22 = a*e - b*d;
  float det = a*C00 + b*C10 + c*C20;
  float rd = 1.0f / det;
  float tx = px - M1[3], ty = py - M1[7], tz = pz - M1[11];
  float t0 = rd * (C00*tx + C01*ty + C02*tz);
  float t1 = rd * (C10*tx + C11*ty + C12*tz);
  float t2 = rd * (C20*tx + C21*ty + C22*tz);
  float i0 = M2[0]*t0 + M2[1]*t1 + M2[2]*t2  + M2[3];
  float i1 = M2[4]*t0 + M2[5]*t1 + M2[6]*t2  + M2[7];
  float i2 = M2[8]*t0 + M2[9]*t1 + M2[10]*t2 + M2[11];
  float d0 = rd * (C00*dx + C01*dy + C02*dz);
  float d1 = rd * (C10*dx + C11*dy + C12*dz);
  float d2 = rd * (C20*dx + C21*dy + C22*dz);
  float e0 = M2[0]*d0 + M2[1]*d1 + M2[2]*d2;
  float e1 = M2[4]*d0 + M2[5]*d1 + M2[6]*d2;
  float e2 = M2[8]*d0 + M2[9]*d1 + M2[10]*d2;

  size_t k = (size_t)n * PP + p;   // n-major
  out[O1 + k*3+0] = e0; out[O1 + k*3+1] = e1; out[O1 + k*3+2] = e2;
  out[O3 + k] = fl;
  out[O4 + k*3+0] = i0; out[O4 + k*3+1] = i1; out[O4 + k*3+2] = i2;
  out[O5 + k] = pn;
}

// grid: 640 blocks x 128 threads. block b: p = b>>7, 256 n's, 2 per thread
// (amortizes each sPart read over 2 evals). Distance expression and strict-<
// ascending-m tracking bit-identical to the R8-passing version.
__global__ __launch_bounds__(128) void nn_kernel(
    const float* __restrict__ pp0, const float* __restrict__ pp1,
    const float* __restrict__ part_pts, const float* __restrict__ pbw,
    const float* __restrict__ Ag, const float* __restrict__ Bg,
    const int* __restrict__ lengths2, float* __restrict__ out)
{
  __shared__ float4 sPart[MM];   // {x, y, z, |y|^2}
  __shared__ float4 sA4[72];
  __shared__ float4 sB4[72];
  int t = threadIdx.x;
  int p = blockIdx.x >> 7;
  int n0 = (blockIdx.x & 127) << 8;

  // pose-pair disambiguation (wave-uniform); pose_dirs rows unit-norm
  float s0r0 = pp0[0], s0r1 = pp0[1], s0r2 = pp0[2];
  float nrm = s0r0*s0r0 + s0r1*s0r1 + s0r2*s0r2;
  bool c0_is_dirs = fabsf(nrm - 1.0f) < 1e-4f;
  const float* pose_pts  = c0_is_dirs ? pp1 : pp0;
  const float* pose_dirs = c0_is_dirs ? pp0 : pp1;

  {
    #pragma clang fp contract(off)
    for (int i = t; i < MM; i += 128) {
      float x = part_pts[((size_t)p*MM+i)*3+0];
      float y = part_pts[((size_t)p*MM+i)*3+1];
      float z = part_pts[((size_t)p*MM+i)*3+2];
      float yy = ((x*x) + (y*y)) + (z*z);
      sPart[i] = make_float4(x, y, z, yy);
    }
  }
  for (int i = t; i < 72; i += 128) {
    int l = i*4;
    int j = l / 12, rc = l % 12;
    float4 qa, qb;
    qa.x = Ag[j*16+rc+0]; qa.y = Ag[j*16+rc+1]; qa.z = Ag[j*16+rc+2]; qa.w = Ag[j*16+rc+3];
    qb.x = Bg[j*16+rc+0]; qb.y = Bg[j*16+rc+1]; qb.z = Bg[j*16+rc+2]; qb.w = Bg[j*16+rc+3];
    sA4[i] = qa; sB4[i] = qb;
  }
  int mlen = lengths2[p]; if (mlen > MM) mlen = MM;
  __syncthreads();

  int n_a = n0 + t, n_b = n0 + 128 + t;
  float xa = pose_pts[n_a*3+0], ya = pose_pts[n_a*3+1], za = pose_pts[n_a*3+2];
  float xb = pose_pts[n_b*3+0], yb = pose_pts[n_b*3+1], zb = pose_pts[n_b*3+2];
  float dxa = pose_dirs[n_a*3+0], dya = pose_dirs[n_a*3+1], dza = pose_dirs[n_a*3+2];
  float dxb = pose_dirs[n_b*3+0], dyb = pose_dirs[n_b*3+1], dzb = pose_dirs[n_b*3+2];

  float bestA = 1e30f, bestB = 1e30f;
  int bmA = 0, bmB = 0;
  {
    #pragma clang fp contract(off)
    float x2a = ((xa*xa) + (ya*ya)) + (za*za);
    float x2b = ((xb*xb) + (yb*yb)) + (zb*zb);
    int m = 0;
    for (; m + 3 < mlen; m += 4) {
      float4 q0 = sPart[m+0];
      float4 q1 = sPart[m+1];
      float4 q2 = sPart[m+2];
      float4 q3 = sPart[m+3];
      float dA0 = fmaxf((x2a - (2.0f*(((xa*q0.x) + (ya*q0.y)) + (za*q0.z)))) + q0.w, 0.0f);
      float dA1 = fmaxf((x2a - (2.0f*(((xa*q1.x) + (ya*q1.y)) + (za*q1.z)))) + q1.w, 0.0f);
      float dA2 = fmaxf((x2a - (2.0f*(((xa*q2.x) + (ya*q2.y)) + (za*q2.z)))) + q2.w, 0.0f);
      float dA3 = fmaxf((x2a - (2.0f*(((xa*q3.x) + (ya*q3.y)) + (za*q3.z)))) + q3.w, 0.0f);
      if (dA0 < bestA) { bestA = dA0; bmA = m+0; }
      if (dA1 < bestA) { bestA = dA1; bmA = m+1; }
      if (dA2 < bestA) { bestA = dA2; bmA = m+2; }
      if (dA3 < bestA) { bestA = dA3; bmA = m+3; }
      float dB0 = fmaxf((x2b - (2.0f*(((xb*q0.x) + (yb*q0.y)) + (zb*q0.z)))) + q0.w, 0.0f);
      float dB1 = fmaxf((x2b - (2.0f*(((xb*q1.x) + (yb*q1.y)) + (zb*q1.z)))) + q1.w, 0.0f);
      float dB2 = fmaxf((x2b - (2.0f*(((xb*q2.x) + (yb*q2.y)) + (zb*q2.z)))) + q2.w, 0.0f);
      float dB3 = fmaxf((x2b - (2.0f*(((xb*q3.x) + (yb*q3.y)) + (zb*q3.z)))) + q3.w, 0.0f);
      if (dB0 < bestB) { bestB = dB0; bmB = m+0; }
      if (dB1 < bestB) { bestB = dB1; bmB = m+1; }
      if (dB2 < bestB) { bestB = dB2; bmB = m+2; }
      if (dB3 < bestB) { bestB = dB3; bmB = m+3; }
    }
    for (; m < mlen; ++m) {
      float4 q = sPart[m];
      float dA = fmaxf((x2a - (2.0f*(((xa*q.x) + (ya*q.y)) + (za*q.z)))) + q.w, 0.0f);
      if (dA < bestA) { bestA = dA; bmA = m; }
      float dB = fmaxf((x2b - (2.0f*(((xb*q.x) + (yb*q.y)) + (zb*q.z)))) + q.w, 0.0f);
      if (dB < bestB) { bestB = dB; bmB = m; }
    }
  }
  float pnA = sqrtf(bestA);
  float pnB = sqrtf(bestB);
  float flA = ((double)pnA < 0.08) ? 1.0f : 0.0f;
  float flB = ((double)pnB < 0.08) ? 1.0f : 0.0f;
  transform_one(n_a, p, bmA, pnA, flA, xa, ya, za, dxa, dya, dza, pbw, sA4, sB4, out);
  transform_one(n_b, p, bmB, pnB, flB, xb, yb, zb, dxb, dyb, dzb, pbw, sA4, sB4, out);
}

// ---------------- MLP via bf16 MFMA + LDS-staged W2 ----------------
// grid: 1280 blocks x 256 threads (4 waves); 128 rows/block, 32 rows/wave.
// W2 staged kc-chunk (16 KB) at a time, double-buffered in LDS; the global
// load for chunk kc+1 is issued before the MFMAs of chunk kc (latency hidden),
// ds_write + barrier at the end of each kc.
__global__ __launch_bounds__(256) void mlp_kernel(
    const float* __restrict__ W1g, const float* __restrict__ b1g,
    const float* __restrict__ b2g, const float* __restrict__ W3g,
    const float* __restrict__ b3g, const ushort_t* __restrict__ W2bf,
    float* __restrict__ out)
{
  __shared__ float sPar[2052];    // W1 | b1 | b2 | W3[k][3] | b3
  __shared__ uint4 sW2[2][1024];  // 2 x 16 KB kc-chunks (B-fragment order)
  int t = threadIdx.x;
  int wave = t >> 6, lane = t & 63, quad = lane >> 4, m16 = lane & 15;
  size_t row0 = (size_t)blockIdx.x * 128 + (size_t)wave * 32;

  for (int i = t; i < 2051; i += 256) {
    float v;
    if (i < 768)       v = W1g[i];
    else if (i < 1024) v = b1g[i-768];
    else if (i < 1280) v = b2g[i-1024];
    else if (i < 2048) v = W3g[i-1280];
    else               v = b3g[i-2048];
    sPar[i] = v;
  }

  const uint4* W2u4 = (const uint4*)W2bf;   // chunk kc = W2u4[kc*1024 .. +1024)
  // preload chunk 0
  {
    uint4 l0 = W2u4[0*256 + t];
    uint4 l1 = W2u4[1*256 + t];
    uint4 l2 = W2u4[2*256 + t];
    uint4 l3 = W2u4[3*256 + t];
    sW2[0][0*256 + t] = l0;
    sW2[0][1*256 + t] = l1;
    sW2[0][2*256 + t] = l2;
    sW2[0][3*256 + t] = l3;
  }

  int r0 = (int)row0 + m16;
  int r1 = r0 + 16;
  float x0 = out[O4 + (size_t)r0*3+0], y0 = out[O4 + (size_t)r0*3+1], z0 = out[O4 + (size_t)r0*3+2];
  float x1 = out[O4 + (size_t)r1*3+0], y1 = out[O4 + (size_t)r1*3+1], z1 = out[O4 + (size_t)r1*3+2];
  __syncthreads();

  f32x4 acc0[16], acc1[16];
  #pragma unroll
  for (int nt = 0; nt < 16; ++nt) {
    acc0[nt] = (f32x4){0.f,0.f,0.f,0.f};
    acc1[nt] = (f32x4){0.f,0.f,0.f,0.f};
  }

  for (int kc = 0; kc < 8; ++kc) {
    int cur = kc & 1;
    // issue next chunk's global loads first (latency hides under this kc's math)
    uint4 nl0, nl1, nl2, nl3;
    if (kc < 7) {
      const uint4* src = W2u4 + (kc+1)*1024;
      nl0 = src[0*256 + t];
      nl1 = src[1*256 + t];
      nl2 = src[2*256 + t];
      nl3 = src[3*256 + t];
    }
    // A-fragments for this kc (per-lane, f32 layer-1 + relu + bf16 cvt)
    bf16x8 A0, A1;
    int c0 = kc*32 + quad*8;
    #pragma unroll
    for (int j = 0; j < 8; ++j) {
      int c = c0 + j;
      float w0 = sPar[c], w1 = sPar[256+c], w2 = sPar[512+c], bb = sPar[768+c];
      float h0 = fmaxf(fmaf(z0, w2, fmaf(y0, w1, fmaf(x0, w0, bb))), 0.f);
      float h1 = fmaxf(fmaf(z1, w2, fmaf(y1, w1, fmaf(x1, w0, bb))), 0.f);
      A0[j] = (short)f2bf(h0);
      A1[j] = (short)f2bf(h1);
    }
    const ushort_t* base = (const ushort_t*)&sW2[cur][0];
    #pragma unroll
    for (int nt = 0; nt < 16; ++nt) {
      bf16x8 B = *(const bf16x8*)(base + nt*512 + lane*8);
      acc0[nt] = __builtin_amdgcn_mfma_f32_16x16x32_bf16(A0, B, acc0[nt], 0, 0, 0);
      acc1[nt] = __builtin_amdgcn_mfma_f32_16x16x32_bf16(A1, B, acc1[nt], 0, 0, 0);
    }
    if (kc < 7) {
      uint4* dst = &sW2[1-cur][0];
      dst[0*256 + t] = nl0;
      dst[1*256 + t] = nl1;
      dst[2*256 + t] = nl2;
      dst[3*256 + t] = nl3;
    }
    __syncthreads();
  }

  // epilogue: h2[row=quad*4+reg][col=nt*16+m16]; layer-3 f32 + quad-reduce
  #pragma unroll
  for (int tile = 0; tile < 2; ++tile) {
    #pragma unroll
    for (int reg = 0; reg < 4; ++reg) {
      float p0 = 0.f, p1 = 0.f, p2 = 0.f;
      #pragma unroll
      for (int nt = 0; nt < 16; ++nt) {
        int col = nt*16 + m16;
        float h2v = tile ? acc1[nt][reg] : acc0[nt][reg];
        float h2 = fmaxf(h2v + sPar[1024+col], 0.f);
        p0 = fmaf(h2, sPar[1280+col*3+0], p0);
        p1 = fmaf(h2, sPar[1280+col*3+1], p1);
        p2 = fmaf(h2, sPar[1280+col*3+2], p2);
      }
      #pragma unroll
      for (int mask = 1; mask < 16; mask <<= 1) {
        p0 += __shfl_xor(p0, mask);
        p1 += __shfl_xor(p1, mask);
        p2 += __shfl_xor(p2, mask);
      }
      if (m16 == 0) {
        int r = (int)row0 + tile*16 + quad*4 + reg;
        float fl = out[O3 + r];
        float i0 = out[O4 + (size_t)r*3+0];
        float i1 = out[O4 + (size_t)r*3+1];
        float i2 = out[O4 + (size_t)r*3+2];
        float rr0 = 0.05f * tanh_fast(p0 + sPar[2048]) * fl;
        float rr1 = 0.05f * tanh_fast(p1 + sPar[2049]) * fl;
        float rr2 = 0.05f * tanh_fast(p2 + sPar[2050]) * fl;
        out[O0 + (size_t)r*3+0] = i0 + rr0;
        out[O0 + (size_t)r*3+1] = i1 + rr1;
        out[O0 + (size_t)r*3+2] = i2 + rr2;
        out[O2 + (size_t)r*3+0] = rr0;
        out[O2 + (size_t)r*3+1] = rr1;
        out[O2 + (size_t)r*3+2] = rr2;
      }
    }
  }
}

extern "C" void kernel_launch(void* const* d_in, const int* in_sizes, int n_in,
                              void* d_out, int out_size, void* d_ws, size_t ws_size,
                              hipStream_t stream) {
  (void)out_size; (void)ws_size;
  // size-based slot remap (no-op under documented dict order; protective otherwise)
  const int want[13] = {98304, 98304, 15360, 122880, 384, 384, 768, 256, 65536, 256, 768, 3, 5};
  int idx[13];
  bool used[64] = {false};
  for (int L = 0; L < 13; ++L) {
    idx[L] = -1;
    for (int s = 0; s < n_in && s < 64; ++s) {
      if (!used[s] && in_sizes[s] == want[L]) { idx[L] = s; used[s] = true; break; }
    }
    if (idx[L] < 0) idx[L] = L;
  }
  const float* pp0       = (const float*)d_in[idx[0]];
  const float* pp1       = (const float*)d_in[idx[1]];
  const float* part_pts  = (const float*)d_in[idx[2]];
  const float* part_pbw  = (const float*)d_in[idx[3]];
  const float* A         = (const float*)d_in[idx[4]];
  const float* bigA      = (const float*)d_in[idx[5]];
  const float* W1        = (const float*)d_in[idx[6]];
  const float* b1        = (const float*)d_in[idx[7]];
  const float* W2        = (const float*)d_in[idx[8]];
  const float* b2        = (const float*)d_in[idx[9]];
  const float* W3        = (const float*)d_in[idx[10]];
  const float* b3        = (const float*)d_in[idx[11]];
  const int*   lengths2  = (const int*)d_in[idx[12]];
  float* out = (float*)d_out;
  ushort_t* W2bf = (ushort_t*)d_ws;   // 128 KB of workspace

  prep_w2<<<256, 256, 0, stream>>>(W2, W2bf);
  nn_kernel<<<640, 128, 0, stream>>>(pp0, pp1, part_pts, part_pbw,
                                     A, bigA, lengths2, out);
  mlp_kernel<<<1280, 256, 0, stream>>>(W1, b1, b2, W3, b3, W2bf, out);
}

// Round 12
// 249.389 us; speedup vs baseline: 1.3413x; 1.3413x over previous
//
#include <hip/hip_runtime.h>
#include <stdint.h>
#include <math.h>

// Problem constants
#define NPTS 32768
#define PP   5
#define MM   1024
#define JJ   24
#define HH   256

// out (f32 element offsets), total 2,293,760 floats
#define O0 0                // tpose        [1,N,P,3]
#define O1 491520           // tpose_dirs   [1,N,P,3]
#define O2 983040           // resd         [1,N,P,3]
#define O3 1474560          // pflag        [1,N,P]
#define O4 1638400          // init_bigpose [1,N*P,3]
#define O5 2129920          // pnorm        [1,N*P]

typedef unsigned short ushort_t;
typedef unsigned int   uint_t;
typedef __attribute__((ext_vector_type(8))) short bf16x8;
typedef __attribute__((ext_vector_type(4))) float f32x4;

__device__ __forceinline__ ushort_t f2bf(float f) {
  union { uint_t i; float f; } v; v.f = f;
  uint_t i = v.i;
  return (ushort_t)((i + 0x7FFFu + ((i >> 16) & 1u)) >> 16);  // RNE
}
__device__ __forceinline__ float tanh_fast(float v) {
  v = fminf(fmaxf(v, -15.f), 15.f);
  float e = __expf(2.f*v);
  return __fdividef(e - 1.f, e + 1.f);   // abs err < 1e-6
}

// ---------------- prep: W2 f32 -> bf16 in MFMA B-fragment order ----------------
// idx = kc*8192 + tile*512 + lane*8 + j  (lane=quad*16+(n&15), quad=(k&31)>>3, j=k&7)
__global__ __launch_bounds__(256) void prep_w2(const float* __restrict__ W2g,
                                               ushort_t* __restrict__ W2bf)
{
  int k = blockIdx.x;
  int n = threadIdx.x;
  float v = W2g[k*256 + n];
  int kc = k >> 5, quad = (k & 31) >> 3, j = k & 7;
  int tile = n >> 4, lane = quad*16 + (n & 15);
  W2bf[kc*8192 + tile*512 + lane*8 + j] = f2bf(v);
}

// ---------------- fused: NN + transform + MLP ----------------
// grid 256 x 256 threads; block = 128 n x 5 p = 640 rows, k = n0*5 + l.
__global__ __launch_bounds__(256) void fused_kernel(
    const float* __restrict__ pp0, const float* __restrict__ pp1,
    const float* __restrict__ part_pts, const float* __restrict__ pbw,
    const float* __restrict__ Ag, const float* __restrict__ Bg,
    const float* __restrict__ W1g, const float* __restrict__ b1g,
    const float* __restrict__ b2g, const float* __restrict__ W3g,
    const float* __restrict__ b3g, const int* __restrict__ lengths2,
    const ushort_t* __restrict__ W2bf, float* __restrict__ out)
{
  __shared__ float4 sA4[72];       // A rows 0..2 per joint
  __shared__ float4 sB4[72];       // big_A rows 0..2 per joint
  __shared__ float  sPar[2052];    // W1 | b1 | b2 | W3[k][3] | b3
  __shared__ float  sIBP[640*3];   // init_bigpose (block rows)
  __shared__ float  sPn[640];      // d2 then pn
  __shared__ int    sBM[640];      // argmin index
  __shared__ float  sPose[128*3];
  __shared__ float  sDirs[128*3];
  __shared__ float4 sPart[MM];     // one p's {x,y,z,|y|^2} at a time
  // total LDS = 42768 B

  int t = threadIdx.x;
  int n0 = blockIdx.x << 7;
  size_t kbase = (size_t)n0 * 5;

  // pose-pair disambiguation (wave-uniform); pose_dirs rows unit-norm
  float s0r0 = pp0[0], s0r1 = pp0[1], s0r2 = pp0[2];
  float nrm = s0r0*s0r0 + s0r1*s0r1 + s0r2*s0r2;
  bool c0_is_dirs = fabsf(nrm - 1.0f) < 1e-4f;
  const float* pose_pts  = c0_is_dirs ? pp1 : pp0;
  const float* pose_dirs = c0_is_dirs ? pp0 : pp1;

  // ---- Phase A: params + block pose into LDS ----
  for (int i = t; i < 72; i += 256) {
    int l4 = i*4;                  // l4%12 in {0,4,8}: never crosses a joint row
    int j = l4 / 12, rc = l4 % 12;
    float4 qa, qb;
    qa.x = Ag[j*16+rc+0]; qa.y = Ag[j*16+rc+1]; qa.z = Ag[j*16+rc+2]; qa.w = Ag[j*16+rc+3];
    qb.x = Bg[j*16+rc+0]; qb.y = Bg[j*16+rc+1]; qb.z = Bg[j*16+rc+2]; qb.w = Bg[j*16+rc+3];
    sA4[i] = qa; sB4[i] = qb;
  }
  for (int i = t; i < 2051; i += 256) {
    float v;
    if (i < 768)       v = W1g[i];
    else if (i < 1024) v = b1g[i-768];
    else if (i < 1280) v = b2g[i-1024];
    else if (i < 2048) v = W3g[i-1280];
    else               v = b3g[i-2048];
    sPar[i] = v;
  }
  for (int i = t; i < 384; i += 256) {
    sPose[i] = pose_pts[(size_t)n0*3 + i];
    sDirs[i] = pose_dirs[(size_t)n0*3 + i];
  }

  // ---- Phase B: NN, p sequential, 4 slices/point ----
  for (int p = 0; p < PP; ++p) {
    {
      #pragma clang fp contract(off)
      for (int i = t; i < MM; i += 256) {
        float x = part_pts[((size_t)p*MM+i)*3+0];
        float y = part_pts[((size_t)p*MM+i)*3+1];
        float z = part_pts[((size_t)p*MM+i)*3+2];
        float yy = ((x*x) + (y*y)) + (z*z);   // np: sequential, no FMA
        sPart[i] = make_float4(x, y, z, yy);
      }
    }
    int mlen = lengths2[p]; if (mlen > MM) mlen = MM;
    __syncthreads();   // sPart ready (also covers Phase A on p==0)

    #pragma unroll
    for (int half = 0; half < 2; ++half) {
      int ti = t + (half << 8);
      int ln = ti >> 2, s = ti & 3;
      float xa = sPose[ln*3+0], ya = sPose[ln*3+1], za = sPose[ln*3+2];
      float best = 1e30f; int bm = 0;
      {
        #pragma clang fp contract(off)
        float x2 = ((xa*xa) + (ya*ya)) + (za*za);
        int m = s;
        for (; m + 28 < mlen; m += 32) {
          float4 q[8];
          #pragma unroll
          for (int i = 0; i < 8; ++i) q[i] = sPart[m + 4*i];
          #pragma unroll
          for (int i = 0; i < 8; ++i) {
            float dt = ((xa*q[i].x) + (ya*q[i].y)) + (za*q[i].z);
            float dd = fmaxf((x2 - (2.0f*dt)) + q[i].w, 0.0f);
            if (dd < best) { best = dd; bm = m + 4*i; }   // strict <, ascending m
          }
        }
        for (; m < mlen; m += 4) {
          float4 q = sPart[m];
          float dt = ((xa*q.x) + (ya*q.y)) + (za*q.z);
          float dd = fmaxf((x2 - (2.0f*dt)) + q.w, 0.0f);
          if (dd < best) { best = dd; bm = m; }
        }
      }
      // combine 4 slices (lanes of one quad); exact first-min tie rule
      float od = __shfl_xor(best, 1); int om = __shfl_xor(bm, 1);
      if (od < best || (od == best && om < bm)) { best = od; bm = om; }
      od = __shfl_xor(best, 2); om = __shfl_xor(bm, 2);
      if (od < best || (od == best && om < bm)) { best = od; bm = om; }
      if (s == 0) { int l = ln*5 + p; sPn[l] = best; sBM[l] = bm; }
    }
    __syncthreads();   // before next p overwrites sPart
  }

  // ---- Phase C: transform (verbatim math), writes O1/O3/O4/O5 + LDS relay ----
  for (int l = t; l < 640; l += 256) {
    int ln = l / 5, p = l % 5;
    float px = sPose[ln*3+0], py = sPose[ln*3+1], pz = sPose[ln*3+2];
    float dx = sDirs[ln*3+0], dy = sDirs[ln*3+1], dz = sDirs[ln*3+2];
    int nn = sBM[l];
    float pn = sqrtf(sPn[l]);
    float fl = ((double)pn < 0.08) ? 1.0f : 0.0f;
    sPn[l] = pn;

    const float4* bwr = (const float4*)(pbw + ((size_t)p * MM + nn) * JJ);
    float bw[24];
    #pragma unroll
    for (int q = 0; q < 6; ++q) {
      float4 u = bwr[q];
      bw[q*4+0] = u.x; bw[q*4+1] = u.y; bw[q*4+2] = u.z; bw[q*4+3] = u.w;
    }
    float M1[12], M2[12];
    #pragma unroll
    for (int q = 0; q < 12; ++q) { M1[q] = 0.f; M2[q] = 0.f; }
    #pragma unroll
    for (int j = 0; j < 24; ++j) {
      float w = bw[j];
      float4 a0 = sA4[j*3+0], a1 = sA4[j*3+1], a2 = sA4[j*3+2];
      M1[0]=fmaf(w,a0.x,M1[0]); M1[1]=fmaf(w,a0.y,M1[1]); M1[2]=fmaf(w,a0.z,M1[2]); M1[3]=fmaf(w,a0.w,M1[3]);
      M1[4]=fmaf(w,a1.x,M1[4]); M1[5]=fmaf(w,a1.y,M1[5]); M1[6]=fmaf(w,a1.z,M1[6]); M1[7]=fmaf(w,a1.w,M1[7]);
      M1[8]=fmaf(w,a2.x,M1[8]); M1[9]=fmaf(w,a2.y,M1[9]); M1[10]=fmaf(w,a2.z,M1[10]); M1[11]=fmaf(w,a2.w,M1[11]);
      float4 c0 = sB4[j*3+0], c1 = sB4[j*3+1], c2 = sB4[j*3+2];
      M2[0]=fmaf(w,c0.x,M2[0]); M2[1]=fmaf(w,c0.y,M2[1]); M2[2]=fmaf(w,c0.z,M2[2]); M2[3]=fmaf(w,c0.w,M2[3]);
      M2[4]=fmaf(w,c1.x,M2[4]); M2[5]=fmaf(w,c1.y,M2[5]); M2[6]=fmaf(w,c1.z,M2[6]); M2[7]=fmaf(w,c1.w,M2[7]);
      M2[8]=fmaf(w,c2.x,M2[8]); M2[9]=fmaf(w,c2.y,M2[9]); M2[10]=fmaf(w,c2.z,M2[10]); M2[11]=fmaf(w,c2.w,M2[11]);
    }
    float a=M1[0], b=M1[1], c=M1[2];
    float d=M1[4], e=M1[5], f=M1[6];
    float g=M1[8], h=M1[9], i=M1[10];
    float C00 = e*i - f*h, C01 = c*h - b*i, C02 = b*f - c*e;
    float C10 = f*g - d*i, C11 = a*i - c*g, C12 = c*d - a*f;
    float C20 = d*h - e*g, C21 = b*g - a*h, C22 = a*e - b*d;
    float det = a*C00 + b*C10 + c*C20;
    float rd = 1.0f / det;
    float tx = px - M1[3], ty = py - M1[7], tz = pz - M1[11];
    float t0 = rd * (C00*tx + C01*ty + C02*tz);
    float t1 = rd * (C10*tx + C11*ty + C12*tz);
    float t2 = rd * (C20*tx + C21*ty + C22*tz);
    float i0 = M2[0]*t0 + M2[1]*t1 + M2[2]*t2  + M2[3];
    float i1 = M2[4]*t0 + M2[5]*t1 + M2[6]*t2  + M2[7];
    float i2 = M2[8]*t0 + M2[9]*t1 + M2[10]*t2 + M2[11];
    float d0 = rd * (C00*dx + C01*dy + C02*dz);
    float d1 = rd * (C10*dx + C11*dy + C12*dz);
    float d2 = rd * (C20*dx + C21*dy + C22*dz);
    float e0 = M2[0]*d0 + M2[1]*d1 + M2[2]*d2;
    float e1 = M2[4]*d0 + M2[5]*d1 + M2[6]*d2;
    float e2 = M2[8]*d0 + M2[9]*d1 + M2[10]*d2;

    size_t k = kbase + l;
    out[O1 + k*3+0] = e0; out[O1 + k*3+1] = e1; out[O1 + k*3+2] = e2;
    out[O3 + k] = fl;
    out[O4 + k*3+0] = i0; out[O4 + k*3+1] = i1; out[O4 + k*3+2] = i2;
    out[O5 + k] = pn;
    sIBP[l*3+0] = i0; sIBP[l*3+1] = i1; sIBP[l*3+2] = i2;
  }
  __syncthreads();

  // ---- Phase D: MLP (R10 structure; 5 tile-pairs/wave, B from L2 W2bf) ----
  int wave = t >> 6, lane = t & 63, quad = lane >> 4, m16 = lane & 15;
  for (int pi = 0; pi < 5; ++pi) {
    int pr = wave + (pi << 2);       // 20 pairs
    int row0 = pr << 5;              // local row base (32 rows)
    int r0 = row0 + m16, r1 = r0 + 16;
    float x0 = sIBP[r0*3+0], y0 = sIBP[r0*3+1], z0 = sIBP[r0*3+2];
    float x1 = sIBP[r1*3+0], y1 = sIBP[r1*3+1], z1 = sIBP[r1*3+2];

    f32x4 acc0[16], acc1[16];
    #pragma unroll
    for (int nt = 0; nt < 16; ++nt) {
      acc0[nt] = (f32x4){0.f,0.f,0.f,0.f};
      acc1[nt] = (f32x4){0.f,0.f,0.f,0.f};
    }
    for (int kc = 0; kc < 8; ++kc) {
      bf16x8 A0, A1;
      int c0 = kc*32 + quad*8;
      #pragma unroll
      for (int j = 0; j < 8; ++j) {
        int c = c0 + j;
        float w0 = sPar[c], w1 = sPar[256+c], w2 = sPar[512+c], bb = sPar[768+c];
        float h0 = fmaxf(fmaf(z0, w2, fmaf(y0, w1, fmaf(x0, w0, bb))), 0.f);
        float h1 = fmaxf(fmaf(z1, w2, fmaf(y1, w1, fmaf(x1, w0, bb))), 0.f);
        A0[j] = (short)f2bf(h0);
        A1[j] = (short)f2bf(h1);
      }
      const ushort_t* Wk = W2bf + kc*8192 + lane*8;
      #pragma unroll
      for (int nt = 0; nt < 16; ++nt) {
        bf16x8 B = *(const bf16x8*)(Wk + nt*512);
        acc0[nt] = __builtin_amdgcn_mfma_f32_16x16x32_bf16(A0, B, acc0[nt], 0, 0, 0);
        acc1[nt] = __builtin_amdgcn_mfma_f32_16x16x32_bf16(A1, B, acc1[nt], 0, 0, 0);
      }
    }
    // epilogue: h2[row=quad*4+reg][col=nt*16+m16]
    #pragma unroll
    for (int tile = 0; tile < 2; ++tile) {
      #pragma unroll
      for (int reg = 0; reg < 4; ++reg) {
        float p0 = 0.f, p1 = 0.f, p2 = 0.f;
        #pragma unroll
        for (int nt = 0; nt < 16; ++nt) {
          int col = nt*16 + m16;
          float h2v = tile ? acc1[nt][reg] : acc0[nt][reg];
          float h2 = fmaxf(h2v + sPar[1024+col], 0.f);
          p0 = fmaf(h2, sPar[1280+col*3+0], p0);
          p1 = fmaf(h2, sPar[1280+col*3+1], p1);
          p2 = fmaf(h2, sPar[1280+col*3+2], p2);
        }
        #pragma unroll
        for (int mask = 1; mask < 16; mask <<= 1) {
          p0 += __shfl_xor(p0, mask);
          p1 += __shfl_xor(p1, mask);
          p2 += __shfl_xor(p2, mask);
        }
        if (m16 == 0) {
          int l = row0 + tile*16 + quad*4 + reg;
          float pn = sPn[l];
          float fl = ((double)pn < 0.08) ? 1.0f : 0.0f;
          float i0 = sIBP[l*3+0], i1 = sIBP[l*3+1], i2 = sIBP[l*3+2];
          float rr0 = 0.05f * tanh_fast(p0 + sPar[2048]) * fl;
          float rr1 = 0.05f * tanh_fast(p1 + sPar[2049]) * fl;
          float rr2 = 0.05f * tanh_fast(p2 + sPar[2050]) * fl;
          size_t k = kbase + l;
          out[O0 + k*3+0] = i0 + rr0;
          out[O0 + k*3+1] = i1 + rr1;
          out[O0 + k*3+2] = i2 + rr2;
          out[O2 + k*3+0] = rr0;
          out[O2 + k*3+1] = rr1;
          out[O2 + k*3+2] = rr2;
        }
      }
    }
  }
}

extern "C" void kernel_launch(void* const* d_in, const int* in_sizes, int n_in,
                              void* d_out, int out_size, void* d_ws, size_t ws_size,
                              hipStream_t stream) {
  (void)out_size; (void)ws_size;
  // size-based slot remap (no-op under documented dict order; protective otherwise)
  const int want[13] = {98304, 98304, 15360, 122880, 384, 384, 768, 256, 65536, 256, 768, 3, 5};
  int idx[13];
  bool used[64] = {false};
  for (int L = 0; L < 13; ++L) {
    idx[L] = -1;
    for (int s = 0; s < n_in && s < 64; ++s) {
      if (!used[s] && in_sizes[s] == want[L]) { idx[L] = s; used[s] = true; break; }
    }
    if (idx[L] < 0) idx[L] = L;
  }
  const float* pp0       = (const float*)d_in[idx[0]];
  const float* pp1       = (const float*)d_in[idx[1]];
  const float* part_pts  = (const float*)d_in[idx[2]];
  const float* part_pbw  = (const float*)d_in[idx[3]];
  const float* A         = (const float*)d_in[idx[4]];
  const float* bigA      = (const float*)d_in[idx[5]];
  const float* W1        = (const float*)d_in[idx[6]];
  const float* b1        = (const float*)d_in[idx[7]];
  const float* W2        = (const float*)d_in[idx[8]];
  const float* b2        = (const float*)d_in[idx[9]];
  const float* W3        = (const float*)d_in[idx[10]];
  const float* b3        = (const float*)d_in[idx[11]];
  const int*   lengths2  = (const int*)d_in[idx[12]];
  float* out = (float*)d_out;
  ushort_t* W2bf = (ushort_t*)d_ws;   // 128 KB of workspace

  prep_w2<<<256, 256, 0, stream>>>(W2, W2bf);
  fused_kernel<<<256, 256, 0, stream>>>(pp0, pp1, part_pts, part_pbw,
                                        A, bigA, W1, b1, b2, W3, b3,
                                        lengths2, W2bf, out);
}